// Round 7
// baseline (713.762 us; speedup 1.0000x reference)
//
#include <hip/hip_runtime.h>
#include <stdint.h>

#define B_   16
#define L_   2048
#define D_   256
#define NROW (B_*L_)

#define EPAD 40    // Es row stride (shorts), 80 B (16B-aligned)
#define TPAD 66    // qkv transpose buffer row stride

typedef __attribute__((ext_vector_type(8)))  short s8v;   // 8 x bf16
typedef __attribute__((ext_vector_type(4)))  float f4v;   // 16x16 acc
typedef __attribute__((ext_vector_type(16))) float f16v;  // 32x32 acc

__device__ __forceinline__ unsigned short f2b(float f) {   // RNE f32->bf16
    unsigned u = __builtin_bit_cast(unsigned, f);
    return (unsigned short)((u + 0x7fffu + ((u >> 16) & 1u)) >> 16);
}

// ---------------- K1: QKV projection, 3 balanced types ----------------
// grid (512 row-blocks, 3 types[Q,K,V]), block 256 (4 waves). Each block:
// stage its input tile once, loop 4 weight col-tiles (W stays L2-hot).
__global__ __launch_bounds__(256) void qkv_kernel(
    const float* __restrict__ x, const float* __restrict__ y,
    const float* __restrict__ Wq, const float* __restrict__ Wk, const float* __restrict__ Wv,
    unsigned short* __restrict__ Qb, unsigned short* __restrict__ Kb,
    unsigned short* __restrict__ Vt,
    float* __restrict__ qn, float* __restrict__ kn)
{
    __shared__ unsigned short Xs[64*256];    // 32 KB input tile (bf16)
    __shared__ unsigned short Ws[64*256];    // 32 KB weight tile (bf16)
    __shared__ unsigned short Ts[64*TPAD];   // V transpose buffer

    const int t    = threadIdx.x;
    const int r0   = blockIdx.x * 64;   // global row (flat b*L + pos)
    const int type = blockIdx.y;        // 0=Q 1=K 2=V

    const float* X = (type == 0) ? x : y;
    const float* W = (type == 0) ? Wq : (type == 1) ? Wk : Wv;

    // Stage X tile [64][256] fp32 -> bf16 LDS, 16B-chunk swizzled by row&15.
    #pragma unroll
    for (int p = 0; p < 16; ++p) {
        int idx  = p*256 + t;
        int row  = idx >> 6;
        int half = idx & 1;
        int blk  = (idx & 63) >> 1;
        int c4   = blk*8 + half*4;
        float4 vx = *(const float4*)(X + (size_t)(r0+row)*D_ + c4);
        uint2 px;
        px.x = (unsigned)f2b(vx.x) | ((unsigned)f2b(vx.y) << 16);
        px.y = (unsigned)f2b(vx.z) | ((unsigned)f2b(vx.w) << 16);
        *(uint2*)(Xs + row*256 + (blk ^ (row & 15))*8 + half*4) = px;
    }

    const int w = t >> 6, lane = t & 63, q16 = lane & 15, quad = lane >> 4;
    const int m0 = w * 16;

    float p4[4] = {0.f, 0.f, 0.f, 0.f};
    const f4v z4 = {0.f, 0.f, 0.f, 0.f};

    for (int ct = 0; ct < 4; ++ct) {
        const int e0 = ct * 64;
        __syncthreads();   // prev readers done (covers Xs stage on ct=0)
        #pragma unroll
        for (int p = 0; p < 16; ++p) {
            int idx  = p*256 + t;
            int row  = idx >> 6;
            int half = idx & 1;
            int blk  = (idx & 63) >> 1;
            int c4   = blk*8 + half*4;
            float4 vw = *(const float4*)(W + (size_t)(e0+row)*D_ + c4);
            uint2 pw;
            pw.x = (unsigned)f2b(vw.x) | ((unsigned)f2b(vw.y) << 16);
            pw.y = (unsigned)f2b(vw.z) | ((unsigned)f2b(vw.w) << 16);
            *(uint2*)(Ws + row*256 + (blk ^ (row & 15))*8 + half*4) = pw;
        }
        __syncthreads();

        f4v acc[4];
        #pragma unroll
        for (int n = 0; n < 4; ++n) acc[n] = z4;
        #pragma unroll
        for (int c = 0; c < 8; ++c) {
            s8v a = *(const s8v*)(Xs + (m0 + q16)*256 + (((c*4+quad) ^ q16)*8));
            #pragma unroll
            for (int n = 0; n < 4; ++n) {
                s8v bb = *(const s8v*)(Ws + (n*16 + q16)*256 + (((c*4+quad) ^ q16)*8));
                acc[n] = __builtin_amdgcn_mfma_f32_16x16x32_bf16(a, bb, acc[n], 0, 0, 0);
            }
        }

        if (type < 2) {
            unsigned short* Out = (type == 0) ? Qb : Kb;
            #pragma unroll
            for (int n = 0; n < 4; ++n)
                #pragma unroll
                for (int r = 0; r < 4; ++r) {
                    float v = acc[n][r];
                    p4[r] += v * v;
                    Out[(size_t)(r0 + m0 + quad*4 + r)*D_ + e0 + n*16 + q16] = f2b(v);
                }
        } else {
            // V: transpose via LDS, write Vt[b][d][k] coalesced
            #pragma unroll
            for (int n = 0; n < 4; ++n)
                #pragma unroll
                for (int r = 0; r < 4; ++r)
                    Ts[(m0 + quad*4 + r)*TPAD + n*16 + q16] = f2b(acc[n][r]);
            __syncthreads();
            int j    = t >> 2;
            int kseg = t & 3;
            unsigned pk[8];
            #pragma unroll
            for (int i = 0; i < 8; ++i) {
                unsigned lo = Ts[(kseg*16 + 2*i    )*TPAD + j];
                unsigned hi = Ts[(kseg*16 + 2*i + 1)*TPAD + j];
                pk[i] = lo | (hi << 16);
            }
            int bb_ = r0 >> 11;
            int k0g = r0 & (L_ - 1);
            unsigned short* dst = Vt + (size_t)(bb_*D_ + e0 + j)*L_ + k0g + kseg*16;
            *(uint4*)dst       = make_uint4(pk[0], pk[1], pk[2], pk[3]);
            *((uint4*)dst + 1) = make_uint4(pk[4], pk[5], pk[6], pk[7]);
        }
    }

    if (type < 2) {
        float* norm = (type == 0) ? qn : kn;
        #pragma unroll
        for (int r = 0; r < 4; ++r) {
            float v = p4[r];
            v += __shfl_xor(v, 1, 16);
            v += __shfl_xor(v, 2, 16);
            v += __shfl_xor(v, 4, 16);
            v += __shfl_xor(v, 8, 16);
            if (q16 == 0) norm[r0 + m0 + quad*4 + r] = v;
        }
    }
}

// -------- K2: zero-barrier fused pass, direct-global B-fragments --------
// grid (64 qb, 16 b) = 1024 one-wave blocks -> 4 independent waves/CU.
// Each K/V tile element is consumed by exactly one lane, so LDS staging is
// pure overhead: B-frags loaded straight from global (K,V are L2-resident,
// 1 MB/batch each). No __syncthreads anywhere. Only Es (wave-private 2.5 KB)
// for the C-layout -> A-layout transform; same-wave DS ops are in-order.
// 32x32 layouts: A/B: m|n=lane&31, k=(lane>>5)*8+j. C/D: col=lane&31,
// row=(reg&3)+8*(reg>>2)+4*(lane>>5).
__global__ __launch_bounds__(64) void attnpv_kernel(
    const unsigned short* __restrict__ Qb, const unsigned short* __restrict__ Kb,
    const unsigned short* __restrict__ Vt,
    const float* __restrict__ qn, const float* __restrict__ kn,
    const unsigned char* __restrict__ mask,
    unsigned short* __restrict__ Eb,
    float* __restrict__ rowsum, float* __restrict__ att_out)
{
    __shared__ unsigned short Es[32*EPAD];   // 2.5 KB, wave-private

    const int lane = threadIdx.x;            // 0..63
    const int q0   = blockIdx.x * 32;
    const int b    = blockIdx.y;
    const int bk   = b * L_;
    const int bD   = b * D_;
    const int col  = lane & 31;
    const int h    = lane >> 5;

    const int qrow = bk + q0;

    // Q A-frags in registers: frag c covers k = c*16 + h*8 .. +8, row = col
    s8v qa[16];
    #pragma unroll
    for (int c = 0; c < 16; ++c)
        qa[c] = *(const s8v*)(Qb + (size_t)(qrow + col)*D_ + c*16 + h*8);

    float qnr[16];
    #pragma unroll
    for (int reg = 0; reg < 16; ++reg)
        qnr[reg] = qn[qrow + (reg & 3) + 8*(reg >> 2) + 4*h];

    // E-export addressing: lane -> (row = lane>>1, half-row = lane&1)
    unsigned short* ebase = Eb + (size_t)(qrow + (lane >> 1))*L_ + (lane & 1)*16;
    const unsigned short* esrc = &Es[(lane >> 1)*EPAD + (lane & 1)*16];

    float rs[16];
    #pragma unroll
    for (int reg = 0; reg < 16; ++reg) rs[reg] = 0.f;
    f16v O[8];
    #pragma unroll
    for (int n = 0; n < 8; ++n)
        #pragma unroll
        for (int reg = 0; reg < 16; ++reg) O[n][reg] = 0.f;

    for (int kt = 0; kt < 64; ++kt) {
        const int k0 = kt * 32;

        // V B-frags for this kt: issued first, consumed after the score
        // phase -> ~700 cycles of latency hiding, compiler-pipelined.
        s8v vf[16];
        #pragma unroll
        for (int n = 0; n < 8; ++n) {
            const unsigned short* vr = Vt + (size_t)(bD + n*32 + col)*L_ + k0 + h*8;
            vf[2*n]     = *(const s8v*)vr;
            vf[2*n + 1] = *(const s8v*)(vr + 16);
        }

        const float kc = kn[bk + k0 + col];
        const int   mk = mask[bk + k0 + col];

        // QK^T: B-frag row = col (lane sweeps its own K row along d -> L1-hot)
        const unsigned short* kr = Kb + (size_t)(bk + k0 + col)*D_ + h*8;
        f16v s;
        #pragma unroll
        for (int reg = 0; reg < 16; ++reg) s[reg] = 0.f;
        #pragma unroll
        for (int c = 0; c < 16; ++c) {
            s8v bb = *(const s8v*)(kr + c*16);
            s = __builtin_amdgcn_mfma_f32_32x32x16_bf16(qa[c], bb, s, 0, 0, 0);
        }

        // scores: E = exp(exp(-dist)); Es store = truncation (err ~2e-6)
        #pragma unroll
        for (int reg = 0; reg < 16; ++reg) {
            float d2 = qnr[reg] + kc - 2.0f * s[reg];
            float dist = __builtin_amdgcn_sqrtf(fmaxf(d2, 0.f));
            float E = mk ? 0.f : __expf(__expf(-dist));
            rs[reg] += E;
            Es[((reg & 3) + 8*(reg >> 2) + 4*h)*EPAD + col] =
                (unsigned short)(__builtin_bit_cast(unsigned, E) >> 16);
        }

        // PV: A = Es (32q x 32k, same-wave in-order DS), B = vf
        s8v af0 = *(const s8v*)(&Es[col*EPAD + h*8]);
        s8v af1 = *(const s8v*)(&Es[col*EPAD + 16 + h*8]);
        #pragma unroll
        for (int n = 0; n < 8; ++n) {
            O[n] = __builtin_amdgcn_mfma_f32_32x32x16_bf16(af0, vf[2*n],     O[n], 0, 0, 0);
            O[n] = __builtin_amdgcn_mfma_f32_32x32x16_bf16(af1, vf[2*n + 1], O[n], 0, 0, 0);
        }

        // stream E tile (row-major bf16) for the normalize pass
        *(s8v*)(ebase + k0)     = *(const s8v*)esrc;
        *(s8v*)(ebase + k0 + 8) = *(const s8v*)(esrc + 8);
    }

    // rowsum across the 32 col-lanes; all lanes keep the sum
    float inv[16];
    #pragma unroll
    for (int reg = 0; reg < 16; ++reg) {
        float v = rs[reg];
        v += __shfl_xor(v, 1, 32);
        v += __shfl_xor(v, 2, 32);
        v += __shfl_xor(v, 4, 32);
        v += __shfl_xor(v, 8, 32);
        v += __shfl_xor(v, 16, 32);
        if (col == 0) rowsum[qrow + (reg & 3) + 8*(reg >> 2) + 4*h] = v;
        inv[reg] = 1.0f / v;
    }

    #pragma unroll
    for (int n = 0; n < 8; ++n)
        #pragma unroll
        for (int reg = 0; reg < 16; ++reg)
            att_out[(size_t)(qrow + (reg & 3) + 8*(reg >> 2) + 4*h)*D_ + n*32 + col]
                = O[n][reg] * inv[reg];
}

// -------- K3: attn = E * (1/rowsum), elementwise, HBM-bound --------
__global__ __launch_bounds__(256) void norm_kernel(
    const unsigned short* __restrict__ Eb,
    const float* __restrict__ rowsum,
    float* __restrict__ attn_out)
{
    const int row = blockIdx.x;
    const int t   = threadIdx.x;
    const float inv = 1.0f / rowsum[row];
    const size_t base = (size_t)row * L_ + t*8;

    s8v e = *(const s8v*)(Eb + base);
    float4 o0, o1;
    o0.x = __builtin_bit_cast(float, ((unsigned)(unsigned short)e[0]) << 16) * inv;
    o0.y = __builtin_bit_cast(float, ((unsigned)(unsigned short)e[1]) << 16) * inv;
    o0.z = __builtin_bit_cast(float, ((unsigned)(unsigned short)e[2]) << 16) * inv;
    o0.w = __builtin_bit_cast(float, ((unsigned)(unsigned short)e[3]) << 16) * inv;
    o1.x = __builtin_bit_cast(float, ((unsigned)(unsigned short)e[4]) << 16) * inv;
    o1.y = __builtin_bit_cast(float, ((unsigned)(unsigned short)e[5]) << 16) * inv;
    o1.z = __builtin_bit_cast(float, ((unsigned)(unsigned short)e[6]) << 16) * inv;
    o1.w = __builtin_bit_cast(float, ((unsigned)(unsigned short)e[7]) << 16) * inv;
    *(float4*)(attn_out + base)     = o0;
    *(float4*)(attn_out + base + 4) = o1;
}

extern "C" void kernel_launch(void* const* d_in, const int* in_sizes, int n_in,
                              void* d_out, int out_size, void* d_ws, size_t ws_size,
                              hipStream_t stream) {
    (void)in_sizes; (void)n_in; (void)out_size; (void)ws_size;
    const float* x  = (const float*)d_in[0];
    const float* y  = (const float*)d_in[1];
    const unsigned char* mask = (const unsigned char*)d_in[2];
    const float* Wq = (const float*)d_in[3];
    const float* Wk = (const float*)d_in[4];
    const float* Wv = (const float*)d_in[5];

    // ws: Qb | Kb | Vt (bf16) | qn | kn | rowsum (fp32) | Eb (bf16, 134 MB)
    char* ws = (char*)d_ws;
    unsigned short* Qb = (unsigned short*)ws;
    unsigned short* Kb = Qb + (size_t)NROW * D_;
    unsigned short* Vt = Kb + (size_t)NROW * D_;
    float* qn     = (float*)(ws + 3 * (size_t)NROW * D_ * 2);
    float* kn     = qn + NROW;
    float* rowsum = kn + NROW;
    unsigned short* Eb = (unsigned short*)(rowsum + NROW);

    float* att_out = (float*)d_out;                       // [B, LQ, D]
    float* attn    = att_out + (size_t)NROW * D_;         // [B, LQ, LK]

    qkv_kernel<<<dim3(512, 3), 256, 0, stream>>>(x, y, Wq, Wk, Wv,
                                                 Qb, Kb, Vt, qn, kn);
    attnpv_kernel<<<dim3(64, 16), 64, 0, stream>>>(Qb, Kb, Vt, qn, kn, mask,
                                                   Eb, rowsum, att_out);
    norm_kernel<<<dim3(NROW), 256, 0, stream>>>(Eb, rowsum, attn);
}

// Round 8
// 687.658 us; speedup vs baseline: 1.0380x; 1.0380x over previous
//
#include <hip/hip_runtime.h>
#include <stdint.h>

#define B_   16
#define L_   2048
#define D_   256
#define NROW (B_*L_)

#define EPAD 40    // Es row stride (shorts), 80 B (16B-aligned)
#define TPAD 72    // qkv transpose buffer row stride (144 B, 16B-aligned)

typedef __attribute__((ext_vector_type(8)))  short s8v;   // 8 x bf16
typedef __attribute__((ext_vector_type(4)))  float f4v;   // 16x16 acc
typedef __attribute__((ext_vector_type(16))) float f16v;  // 32x32 acc

__device__ __forceinline__ unsigned short f2b(float f) {   // RNE f32->bf16
    unsigned u = __builtin_bit_cast(unsigned, f);
    return (unsigned short)((u + 0x7fffu + ((u >> 16) & 1u)) >> 16);
}

// ---------------- K1: QKV projection, 3 balanced types ----------------
// grid (512 row-blocks, 3 types[Q,K,V]), block 256 (4 waves).
// type0: Q row-major + qn.  type1: K in B-frag layout Kf + kn.
// type2: V in B-frag layout Vf.  Both K/V reshaped via Ts LDS roundtrip.
// Kf[b][kblk:64][m=d>>3:32][key&31:32][d&7:8]  (8192 shorts per kblk)
// Vf[b][kb=k>>4:128][d:256][kh=(k>>3)&1:2][k&7:8] (4096 shorts per kb)
__global__ __launch_bounds__(256) void qkv_kernel(
    const float* __restrict__ x, const float* __restrict__ y,
    const float* __restrict__ Wq, const float* __restrict__ Wk, const float* __restrict__ Wv,
    unsigned short* __restrict__ Qb, unsigned short* __restrict__ Kf,
    unsigned short* __restrict__ Vf,
    float* __restrict__ qn, float* __restrict__ kn)
{
    __shared__ unsigned short Xs[64*256];    // 32 KB input tile (bf16)
    __shared__ unsigned short Ws[64*256];    // 32 KB weight tile (bf16)
    __shared__ unsigned short Ts[64*TPAD];   // reshape buffer (9 KB)

    const int t    = threadIdx.x;
    const int r0   = blockIdx.x * 64;   // global row (flat b*L + pos)
    const int type = blockIdx.y;        // 0=Q 1=K 2=V

    const float* X = (type == 0) ? x : y;
    const float* W = (type == 0) ? Wq : (type == 1) ? Wk : Wv;

    const int bb_ = r0 >> 11;        // batch
    const int k0g = r0 & (L_ - 1);   // row offset within batch

    // Stage X tile [64][256] fp32 -> bf16 LDS, 16B-chunk swizzled by row&15.
    #pragma unroll
    for (int p = 0; p < 16; ++p) {
        int idx  = p*256 + t;
        int row  = idx >> 6;
        int half = idx & 1;
        int blk  = (idx & 63) >> 1;
        int c4   = blk*8 + half*4;
        float4 vx = *(const float4*)(X + (size_t)(r0+row)*D_ + c4);
        uint2 px;
        px.x = (unsigned)f2b(vx.x) | ((unsigned)f2b(vx.y) << 16);
        px.y = (unsigned)f2b(vx.z) | ((unsigned)f2b(vx.w) << 16);
        *(uint2*)(Xs + row*256 + (blk ^ (row & 15))*8 + half*4) = px;
    }

    const int w = t >> 6, lane = t & 63, q16 = lane & 15, quad = lane >> 4;
    const int m0 = w * 16;

    float p4[4] = {0.f, 0.f, 0.f, 0.f};
    const f4v z4 = {0.f, 0.f, 0.f, 0.f};

    for (int ct = 0; ct < 4; ++ct) {
        const int e0 = ct * 64;
        __syncthreads();   // prev readers done (covers Xs stage on ct=0)
        #pragma unroll
        for (int p = 0; p < 16; ++p) {
            int idx  = p*256 + t;
            int row  = idx >> 6;
            int half = idx & 1;
            int blk  = (idx & 63) >> 1;
            int c4   = blk*8 + half*4;
            float4 vw = *(const float4*)(W + (size_t)(e0+row)*D_ + c4);
            uint2 pw;
            pw.x = (unsigned)f2b(vw.x) | ((unsigned)f2b(vw.y) << 16);
            pw.y = (unsigned)f2b(vw.z) | ((unsigned)f2b(vw.w) << 16);
            *(uint2*)(Ws + row*256 + (blk ^ (row & 15))*8 + half*4) = pw;
        }
        __syncthreads();

        f4v acc[4];
        #pragma unroll
        for (int n = 0; n < 4; ++n) acc[n] = z4;
        #pragma unroll
        for (int c = 0; c < 8; ++c) {
            s8v a = *(const s8v*)(Xs + (m0 + q16)*256 + (((c*4+quad) ^ q16)*8));
            #pragma unroll
            for (int n = 0; n < 4; ++n) {
                s8v bb = *(const s8v*)(Ws + (n*16 + q16)*256 + (((c*4+quad) ^ q16)*8));
                acc[n] = __builtin_amdgcn_mfma_f32_16x16x32_bf16(a, bb, acc[n], 0, 0, 0);
            }
        }

        if (type == 0) {
            // Q: row-major + norm partials
            #pragma unroll
            for (int n = 0; n < 4; ++n)
                #pragma unroll
                for (int r = 0; r < 4; ++r) {
                    float v = acc[n][r];
                    p4[r] += v * v;
                    Qb[(size_t)(r0 + m0 + quad*4 + r)*D_ + e0 + n*16 + q16] = f2b(v);
                }
        } else {
            // K/V: C-layout -> Ts[local row][local d]
            #pragma unroll
            for (int n = 0; n < 4; ++n)
                #pragma unroll
                for (int r = 0; r < 4; ++r) {
                    float v = acc[n][r];
                    if (type == 1) p4[r] += v * v;
                    Ts[(m0 + quad*4 + r)*TPAD + n*16 + q16] = f2b(v);
                }
            __syncthreads();

            if (type == 1) {
                // Kf store: thread t -> kk = t&31, mloc = (t>>5)&7
                int kk = t & 31, mloc = (t >> 5) & 7;
                #pragma unroll
                for (int kb2 = 0; kb2 < 2; ++kb2) {
                    uint4 v4 = *(const uint4*)(Ts + (kb2*32 + kk)*TPAD + mloc*8);
                    *(uint4*)(Kf + (size_t)bb_*524288
                              + (size_t)((k0g >> 5) + kb2)*8192
                              + (size_t)(e0/8 + mloc)*256 + kk*8) = v4;
                }
            } else {
                // Vf store: thread t -> dloc = t&63, kb4 = t>>6
                int dloc = t & 63, kb4 = t >> 6;
                #pragma unroll
                for (int kh = 0; kh < 2; ++kh) {
                    unsigned pk[4];
                    #pragma unroll
                    for (int i2 = 0; i2 < 4; ++i2) {
                        unsigned lo = Ts[(kb4*16 + kh*8 + 2*i2    )*TPAD + dloc];
                        unsigned hi = Ts[(kb4*16 + kh*8 + 2*i2 + 1)*TPAD + dloc];
                        pk[i2] = lo | (hi << 16);
                    }
                    *(uint4*)(Vf + (size_t)bb_*524288
                              + (size_t)((k0g >> 4) + kb4)*4096
                              + (size_t)(e0 + dloc)*16 + kh*8)
                        = make_uint4(pk[0], pk[1], pk[2], pk[3]);
                }
            }
        }
    }

    if (type < 2) {
        float* norm = (type == 0) ? qn : kn;
        #pragma unroll
        for (int r = 0; r < 4; ++r) {
            float v = p4[r];
            v += __shfl_xor(v, 1, 16);
            v += __shfl_xor(v, 2, 16);
            v += __shfl_xor(v, 4, 16);
            v += __shfl_xor(v, 8, 16);
            if (q16 == 0) norm[r0 + m0 + quad*4 + r] = v;
        }
    }
}

// -------- K2: zero-barrier fused pass, COALESCED direct-global B-frags --------
// grid (64 qb, 16 b) = 1024 one-wave blocks. K/V live in B-frag-ordered
// layouts (Kf/Vf), so every wave load is a contiguous 1 KB line-set — no
// LDS staging, no barriers, no DMA. Only the wave-private Es roundtrip.
// 32x32 layouts: A/B: m|n=lane&31, k=(lane>>5)*8+j. C/D: col=lane&31,
// row=(reg&3)+8*(reg>>2)+4*(lane>>5).
__global__ __launch_bounds__(64) void attnpv_kernel(
    const unsigned short* __restrict__ Qb, const unsigned short* __restrict__ Kf,
    const unsigned short* __restrict__ Vf,
    const float* __restrict__ qn, const float* __restrict__ kn,
    const unsigned char* __restrict__ mask,
    unsigned short* __restrict__ Eb,
    float* __restrict__ rowsum, float* __restrict__ att_out)
{
    __shared__ unsigned short Es[32*EPAD];   // 2.5 KB, wave-private

    const int lane = threadIdx.x;            // 0..63
    const int q0   = blockIdx.x * 32;
    const int b    = blockIdx.y;
    const int bk   = b * L_;
    const int col  = lane & 31;
    const int h    = lane >> 5;

    const int qrow = bk + q0;
    const unsigned short* Kfb = Kf + (size_t)b*524288;
    const unsigned short* Vfb = Vf + (size_t)b*524288;

    // Q A-frags (one-time divergent loads, amortized over 64 kt)
    s8v qa[16];
    #pragma unroll
    for (int c = 0; c < 16; ++c)
        qa[c] = *(const s8v*)(Qb + (size_t)(qrow + col)*D_ + c*16 + h*8);

    float qnr[16];
    #pragma unroll
    for (int reg = 0; reg < 16; ++reg)
        qnr[reg] = qn[qrow + (reg & 3) + 8*(reg >> 2) + 4*h];

    // E-export addressing: lane -> (row = lane>>1, half-row = lane&1)
    unsigned short* ebase = Eb + (size_t)(qrow + (lane >> 1))*L_ + (lane & 1)*16;
    const unsigned short* esrc = &Es[(lane >> 1)*EPAD + (lane & 1)*16];

    float rs[16];
    #pragma unroll
    for (int reg = 0; reg < 16; ++reg) rs[reg] = 0.f;
    f16v O[8];
    #pragma unroll
    for (int n = 0; n < 8; ++n)
        #pragma unroll
        for (int reg = 0; reg < 16; ++reg) O[n][reg] = 0.f;

    for (int kt = 0; kt < 64; ++kt) {
        const int k0 = kt * 32;

        // V B-frags (coalesced 1KB per instr), issued early, used in PV
        s8v vf[16];
        #pragma unroll
        for (int n = 0; n < 8; ++n) {
            #pragma unroll
            for (int g = 0; g < 2; ++g)
                vf[n*2 + g] = *(const s8v*)(Vfb + (size_t)(2*kt + g)*4096
                                            + (n*32 + col)*16 + h*8);
        }

        const float kc = kn[bk + k0 + col];
        const int   mk = mask[bk + k0 + col];

        // QK^T: B-frag step c at Kf offset (2c+h)*256 + col*8 (coalesced)
        const unsigned short* kr = Kfb + (size_t)kt*8192 + h*256 + col*8;
        f16v s;
        #pragma unroll
        for (int reg = 0; reg < 16; ++reg) s[reg] = 0.f;
        #pragma unroll
        for (int c = 0; c < 16; ++c) {
            s8v bb = *(const s8v*)(kr + c*512);
            s = __builtin_amdgcn_mfma_f32_32x32x16_bf16(qa[c], bb, s, 0, 0, 0);
        }

        // scores: E = exp(exp(-dist)); Es store truncation-rounded
        #pragma unroll
        for (int reg = 0; reg < 16; ++reg) {
            float d2 = qnr[reg] + kc - 2.0f * s[reg];
            float dist = __builtin_amdgcn_sqrtf(fmaxf(d2, 0.f));
            float E = mk ? 0.f : __expf(__expf(-dist));
            rs[reg] += E;
            Es[((reg & 3) + 8*(reg >> 2) + 4*h)*EPAD + col] =
                (unsigned short)(__builtin_bit_cast(unsigned, E) >> 16);
        }

        // PV: A = Es (same-wave in-order DS), B = vf
        s8v af0 = *(const s8v*)(&Es[col*EPAD + h*8]);
        s8v af1 = *(const s8v*)(&Es[col*EPAD + 16 + h*8]);
        #pragma unroll
        for (int n = 0; n < 8; ++n) {
            O[n] = __builtin_amdgcn_mfma_f32_32x32x16_bf16(af0, vf[2*n],     O[n], 0, 0, 0);
            O[n] = __builtin_amdgcn_mfma_f32_32x32x16_bf16(af1, vf[2*n + 1], O[n], 0, 0, 0);
        }

        // stream E tile (row-major bf16) for the normalize pass
        *(s8v*)(ebase + k0)     = *(const s8v*)esrc;
        *(s8v*)(ebase + k0 + 8) = *(const s8v*)(esrc + 8);
    }

    // rowsum across the 32 col-lanes; all lanes keep the sum
    float inv[16];
    #pragma unroll
    for (int reg = 0; reg < 16; ++reg) {
        float v = rs[reg];
        v += __shfl_xor(v, 1, 32);
        v += __shfl_xor(v, 2, 32);
        v += __shfl_xor(v, 4, 32);
        v += __shfl_xor(v, 8, 32);
        v += __shfl_xor(v, 16, 32);
        if (col == 0) rowsum[qrow + (reg & 3) + 8*(reg >> 2) + 4*h] = v;
        inv[reg] = 1.0f / v;
    }

    #pragma unroll
    for (int n = 0; n < 8; ++n)
        #pragma unroll
        for (int reg = 0; reg < 16; ++reg)
            att_out[(size_t)(qrow + (reg & 3) + 8*(reg >> 2) + 4*h)*D_ + n*32 + col]
                = O[n][reg] * inv[reg];
}

// -------- K3: attn = E * (1/rowsum), elementwise, HBM-bound --------
__global__ __launch_bounds__(256) void norm_kernel(
    const unsigned short* __restrict__ Eb,
    const float* __restrict__ rowsum,
    float* __restrict__ attn_out)
{
    const int row = blockIdx.x;
    const int t   = threadIdx.x;
    const float inv = 1.0f / rowsum[row];
    const size_t base = (size_t)row * L_ + t*8;

    s8v e = *(const s8v*)(Eb + base);
    float4 o0, o1;
    o0.x = __builtin_bit_cast(float, ((unsigned)(unsigned short)e[0]) << 16) * inv;
    o0.y = __builtin_bit_cast(float, ((unsigned)(unsigned short)e[1]) << 16) * inv;
    o0.z = __builtin_bit_cast(float, ((unsigned)(unsigned short)e[2]) << 16) * inv;
    o0.w = __builtin_bit_cast(float, ((unsigned)(unsigned short)e[3]) << 16) * inv;
    o1.x = __builtin_bit_cast(float, ((unsigned)(unsigned short)e[4]) << 16) * inv;
    o1.y = __builtin_bit_cast(float, ((unsigned)(unsigned short)e[5]) << 16) * inv;
    o1.z = __builtin_bit_cast(float, ((unsigned)(unsigned short)e[6]) << 16) * inv;
    o1.w = __builtin_bit_cast(float, ((unsigned)(unsigned short)e[7]) << 16) * inv;
    *(float4*)(attn_out + base)     = o0;
    *(float4*)(attn_out + base + 4) = o1;
}

extern "C" void kernel_launch(void* const* d_in, const int* in_sizes, int n_in,
                              void* d_out, int out_size, void* d_ws, size_t ws_size,
                              hipStream_t stream) {
    (void)in_sizes; (void)n_in; (void)out_size; (void)ws_size;
    const float* x  = (const float*)d_in[0];
    const float* y  = (const float*)d_in[1];
    const unsigned char* mask = (const unsigned char*)d_in[2];
    const float* Wq = (const float*)d_in[3];
    const float* Wk = (const float*)d_in[4];
    const float* Wv = (const float*)d_in[5];

    // ws: Qb | Kf | Vf (bf16, 16.78 MB each) | qn | kn | rowsum | Eb (134 MB)
    char* ws = (char*)d_ws;
    unsigned short* Qb = (unsigned short*)ws;
    unsigned short* Kf = Qb + (size_t)NROW * D_;
    unsigned short* Vf = Kf + (size_t)NROW * D_;
    float* qn     = (float*)(ws + 3 * (size_t)NROW * D_ * 2);
    float* kn     = qn + NROW;
    float* rowsum = kn + NROW;
    unsigned short* Eb = (unsigned short*)(rowsum + NROW);

    float* att_out = (float*)d_out;                       // [B, LQ, D]
    float* attn    = att_out + (size_t)NROW * D_;         // [B, LQ, LK]

    qkv_kernel<<<dim3(512, 3), 256, 0, stream>>>(x, y, Wq, Wk, Wv,
                                                 Qb, Kf, Vf, qn, kn);
    attnpv_kernel<<<dim3(64, 16), 64, 0, stream>>>(Qb, Kf, Vf, qn, kn, mask,
                                                   Eb, rowsum, att_out);
    norm_kernel<<<dim3(NROW), 256, 0, stream>>>(Eb, rowsum, attn);
}

// Round 9
// 660.772 us; speedup vs baseline: 1.0802x; 1.0407x over previous
//
#include <hip/hip_runtime.h>
#include <stdint.h>

#define B_   16
#define L_   2048
#define D_   256
#define NROW (B_*L_)

#define EPAD 40    // Es row stride (shorts), 80 B (16B-aligned)
#define TPAD 72    // qkv transpose buffer row stride (144 B, 16B-aligned)

typedef __attribute__((ext_vector_type(8)))  short s8v;   // 8 x bf16
typedef __attribute__((ext_vector_type(4)))  float f4v;   // 16x16 acc
typedef __attribute__((ext_vector_type(16))) float f16v;  // 32x32 acc

__device__ __forceinline__ unsigned short f2b(float f) {   // RNE f32->bf16
    unsigned u = __builtin_bit_cast(unsigned, f);
    return (unsigned short)((u + 0x7fffu + ((u >> 16) & 1u)) >> 16);
}

// ---------------- K1: QKV projection, 3 balanced types ----------------
// grid (512 row-blocks, 3 types[Q,K,V]), block 256 (4 waves).
// type0: Q row-major + qn.  type1: K in B-frag layout Kf + kn.
// type2: V in B-frag layout Vf.  Both K/V reshaped via Ts LDS roundtrip.
// Kf[b][kblk:64][m=d>>3:32][key&31:32][d&7:8]  (8192 shorts per kblk)
// Vf[b][kb=k>>4:128][d:256][kh=(k>>3)&1:2][k&7:8] (4096 shorts per kb)
__global__ __launch_bounds__(256) void qkv_kernel(
    const float* __restrict__ x, const float* __restrict__ y,
    const float* __restrict__ Wq, const float* __restrict__ Wk, const float* __restrict__ Wv,
    unsigned short* __restrict__ Qb, unsigned short* __restrict__ Kf,
    unsigned short* __restrict__ Vf,
    float* __restrict__ qn, float* __restrict__ kn)
{
    __shared__ unsigned short Xs[64*256];    // 32 KB input tile (bf16)
    __shared__ unsigned short Ws[64*256];    // 32 KB weight tile (bf16)
    __shared__ unsigned short Ts[64*TPAD];   // reshape buffer (9 KB)

    const int t    = threadIdx.x;
    const int r0   = blockIdx.x * 64;   // global row (flat b*L + pos)
    const int type = blockIdx.y;        // 0=Q 1=K 2=V

    const float* X = (type == 0) ? x : y;
    const float* W = (type == 0) ? Wq : (type == 1) ? Wk : Wv;

    const int bb_ = r0 >> 11;        // batch
    const int k0g = r0 & (L_ - 1);   // row offset within batch

    // Stage X tile [64][256] fp32 -> bf16 LDS, 16B-chunk swizzled by row&15.
    #pragma unroll
    for (int p = 0; p < 16; ++p) {
        int idx  = p*256 + t;
        int row  = idx >> 6;
        int half = idx & 1;
        int blk  = (idx & 63) >> 1;
        int c4   = blk*8 + half*4;
        float4 vx = *(const float4*)(X + (size_t)(r0+row)*D_ + c4);
        uint2 px;
        px.x = (unsigned)f2b(vx.x) | ((unsigned)f2b(vx.y) << 16);
        px.y = (unsigned)f2b(vx.z) | ((unsigned)f2b(vx.w) << 16);
        *(uint2*)(Xs + row*256 + (blk ^ (row & 15))*8 + half*4) = px;
    }

    const int w = t >> 6, lane = t & 63, q16 = lane & 15, quad = lane >> 4;
    const int m0 = w * 16;

    float p4[4] = {0.f, 0.f, 0.f, 0.f};
    const f4v z4 = {0.f, 0.f, 0.f, 0.f};

    for (int ct = 0; ct < 4; ++ct) {
        const int e0 = ct * 64;
        __syncthreads();   // prev readers done (covers Xs stage on ct=0)
        #pragma unroll
        for (int p = 0; p < 16; ++p) {
            int idx  = p*256 + t;
            int row  = idx >> 6;
            int half = idx & 1;
            int blk  = (idx & 63) >> 1;
            int c4   = blk*8 + half*4;
            float4 vw = *(const float4*)(W + (size_t)(e0+row)*D_ + c4);
            uint2 pw;
            pw.x = (unsigned)f2b(vw.x) | ((unsigned)f2b(vw.y) << 16);
            pw.y = (unsigned)f2b(vw.z) | ((unsigned)f2b(vw.w) << 16);
            *(uint2*)(Ws + row*256 + (blk ^ (row & 15))*8 + half*4) = pw;
        }
        __syncthreads();

        f4v acc[4];
        #pragma unroll
        for (int n = 0; n < 4; ++n) acc[n] = z4;
        #pragma unroll
        for (int c = 0; c < 8; ++c) {
            s8v a = *(const s8v*)(Xs + (m0 + q16)*256 + (((c*4+quad) ^ q16)*8));
            #pragma unroll
            for (int n = 0; n < 4; ++n) {
                s8v bb = *(const s8v*)(Ws + (n*16 + q16)*256 + (((c*4+quad) ^ q16)*8));
                acc[n] = __builtin_amdgcn_mfma_f32_16x16x32_bf16(a, bb, acc[n], 0, 0, 0);
            }
        }

        if (type == 0) {
            // Q: row-major + norm partials
            #pragma unroll
            for (int n = 0; n < 4; ++n)
                #pragma unroll
                for (int r = 0; r < 4; ++r) {
                    float v = acc[n][r];
                    p4[r] += v * v;
                    Qb[(size_t)(r0 + m0 + quad*4 + r)*D_ + e0 + n*16 + q16] = f2b(v);
                }
        } else {
            // K/V: C-layout -> Ts[local row][local d]
            #pragma unroll
            for (int n = 0; n < 4; ++n)
                #pragma unroll
                for (int r = 0; r < 4; ++r) {
                    float v = acc[n][r];
                    if (type == 1) p4[r] += v * v;
                    Ts[(m0 + quad*4 + r)*TPAD + n*16 + q16] = f2b(v);
                }
            __syncthreads();

            if (type == 1) {
                // Kf store: thread t -> kk = t&31, mloc = (t>>5)&7
                int kk = t & 31, mloc = (t >> 5) & 7;
                #pragma unroll
                for (int kb2 = 0; kb2 < 2; ++kb2) {
                    uint4 v4 = *(const uint4*)(Ts + (kb2*32 + kk)*TPAD + mloc*8);
                    *(uint4*)(Kf + (size_t)bb_*524288
                              + (size_t)((k0g >> 5) + kb2)*8192
                              + (size_t)(e0/8 + mloc)*256 + kk*8) = v4;
                }
            } else {
                // Vf store: thread t -> dloc = t&63, kb4 = t>>6
                int dloc = t & 63, kb4 = t >> 6;
                #pragma unroll
                for (int kh = 0; kh < 2; ++kh) {
                    unsigned pk[4];
                    #pragma unroll
                    for (int i2 = 0; i2 < 4; ++i2) {
                        unsigned lo = Ts[(kb4*16 + kh*8 + 2*i2    )*TPAD + dloc];
                        unsigned hi = Ts[(kb4*16 + kh*8 + 2*i2 + 1)*TPAD + dloc];
                        pk[i2] = lo | (hi << 16);
                    }
                    *(uint4*)(Vf + (size_t)bb_*524288
                              + (size_t)((k0g >> 4) + kb4)*4096
                              + (size_t)(e0 + dloc)*16 + kh*8)
                        = make_uint4(pk[0], pk[1], pk[2], pk[3]);
                }
            }
        }
    }

    if (type < 2) {
        float* norm = (type == 0) ? qn : kn;
        #pragma unroll
        for (int r = 0; r < 4; ++r) {
            float v = p4[r];
            v += __shfl_xor(v, 1, 16);
            v += __shfl_xor(v, 2, 16);
            v += __shfl_xor(v, 4, 16);
            v += __shfl_xor(v, 8, 16);
            if (q16 == 0) norm[r0 + m0 + quad*4 + r] = v;
        }
    }
}

// -------- K2: zero-barrier fused pass, d-split x2 for occupancy --------
// grid (64 qb, 16 b, 2 dz) = 2048 one-wave blocks -> 8 waves/CU, 2/SIMD.
// Each wave: FULL QK score pass (all k -> complete rowsum in-register,
// zero inter-block communication), PV over its HALF of d (O[4] = 64 regs,
// vf = 32 regs: combined budget < 256 -> 2 waves/SIMD). Score work is
// duplicated across dz (VALU was 12% busy; latency hiding pays for it).
// dz==0 additionally exports Eb (bf16 row-major) and rowsum.
// 32x32 layouts: A/B: m|n=lane&31, k=(lane>>5)*8+j. C/D: col=lane&31,
// row=(reg&3)+8*(reg>>2)+4*(lane>>5).
__global__ __launch_bounds__(64) void attnpv_kernel(
    const unsigned short* __restrict__ Qb, const unsigned short* __restrict__ Kf,
    const unsigned short* __restrict__ Vf,
    const float* __restrict__ qn, const float* __restrict__ kn,
    const unsigned char* __restrict__ mask,
    unsigned short* __restrict__ Eb,
    float* __restrict__ rowsum, float* __restrict__ att_out)
{
    __shared__ unsigned short Es[32*EPAD];   // 2.5 KB, wave-private

    const int lane = threadIdx.x;            // 0..63
    const int q0   = blockIdx.x * 32;
    const int b    = blockIdx.y;
    const int dz   = blockIdx.z;             // d-half: 0 or 1
    const int bk   = b * L_;
    const int col  = lane & 31;
    const int h    = lane >> 5;

    const int qrow = bk + q0;
    const unsigned short* Kfb = Kf + (size_t)b*524288;
    const unsigned short* Vfb = Vf + (size_t)b*524288 + (size_t)dz*2048; // d-half offset: dz*128*16

    // Q A-frags (one-time divergent loads, amortized over 64 kt)
    s8v qa[16];
    #pragma unroll
    for (int c = 0; c < 16; ++c)
        qa[c] = *(const s8v*)(Qb + (size_t)(qrow + col)*D_ + c*16 + h*8);

    float qnr[16];
    #pragma unroll
    for (int reg = 0; reg < 16; ++reg)
        qnr[reg] = qn[qrow + (reg & 3) + 8*(reg >> 2) + 4*h];

    // E-export addressing: lane -> (row = lane>>1, half-row = lane&1)
    unsigned short* ebase = Eb + (size_t)(qrow + (lane >> 1))*L_ + (lane & 1)*16;
    const unsigned short* esrc = &Es[(lane >> 1)*EPAD + (lane & 1)*16];

    float rs[16];
    #pragma unroll
    for (int reg = 0; reg < 16; ++reg) rs[reg] = 0.f;
    f16v O[4];
    #pragma unroll
    for (int n = 0; n < 4; ++n)
        #pragma unroll
        for (int reg = 0; reg < 16; ++reg) O[n][reg] = 0.f;

    for (int kt = 0; kt < 64; ++kt) {
        const int k0 = kt * 32;

        // V B-frags for this wave's d-half (coalesced), issued early
        s8v vf[8];
        #pragma unroll
        for (int n = 0; n < 4; ++n) {
            #pragma unroll
            for (int g = 0; g < 2; ++g)
                vf[n*2 + g] = *(const s8v*)(Vfb + (size_t)(2*kt + g)*4096
                                            + (n*32 + col)*16 + h*8);
        }

        const float kc = kn[bk + k0 + col];
        const int   mk = mask[bk + k0 + col];

        // QK^T: two independent 8-deep MFMA chains (shorter dep path)
        const unsigned short* kr = Kfb + (size_t)kt*8192 + h*256 + col*8;
        f16v sa, sb;
        #pragma unroll
        for (int reg = 0; reg < 16; ++reg) { sa[reg] = 0.f; sb[reg] = 0.f; }
        #pragma unroll
        for (int c = 0; c < 8; ++c) {
            s8v b0 = *(const s8v*)(kr + c*512);
            s8v b1 = *(const s8v*)(kr + (c + 8)*512);
            sa = __builtin_amdgcn_mfma_f32_32x32x16_bf16(qa[c],     b0, sa, 0, 0, 0);
            sb = __builtin_amdgcn_mfma_f32_32x32x16_bf16(qa[c + 8], b1, sb, 0, 0, 0);
        }

        // scores: E = exp(exp(-dist)); Es store truncation-rounded
        #pragma unroll
        for (int reg = 0; reg < 16; ++reg) {
            float d2 = qnr[reg] + kc - 2.0f * (sa[reg] + sb[reg]);
            float dist = __builtin_amdgcn_sqrtf(fmaxf(d2, 0.f));
            float E = mk ? 0.f : __expf(__expf(-dist));
            rs[reg] += E;
            Es[((reg & 3) + 8*(reg >> 2) + 4*h)*EPAD + col] =
                (unsigned short)(__builtin_bit_cast(unsigned, E) >> 16);
        }

        // dz==0 exports the E tile (row-major bf16) while PV runs
        if (dz == 0) {
            *(s8v*)(ebase + k0)     = *(const s8v*)esrc;
            *(s8v*)(ebase + k0 + 8) = *(const s8v*)(esrc + 8);
        }

        // PV: A = Es (same-wave in-order DS), B = vf (4 d-tiles)
        s8v af0 = *(const s8v*)(&Es[col*EPAD + h*8]);
        s8v af1 = *(const s8v*)(&Es[col*EPAD + 16 + h*8]);
        #pragma unroll
        for (int n = 0; n < 4; ++n) {
            O[n] = __builtin_amdgcn_mfma_f32_32x32x16_bf16(af0, vf[2*n],     O[n], 0, 0, 0);
            O[n] = __builtin_amdgcn_mfma_f32_32x32x16_bf16(af1, vf[2*n + 1], O[n], 0, 0, 0);
        }
    }

    // rowsum across the 32 col-lanes; all lanes keep the sum (complete: all k)
    float inv[16];
    #pragma unroll
    for (int reg = 0; reg < 16; ++reg) {
        float v = rs[reg];
        v += __shfl_xor(v, 1, 32);
        v += __shfl_xor(v, 2, 32);
        v += __shfl_xor(v, 4, 32);
        v += __shfl_xor(v, 8, 32);
        v += __shfl_xor(v, 16, 32);
        if (dz == 0 && col == 0) rowsum[qrow + (reg & 3) + 8*(reg >> 2) + 4*h] = v;
        inv[reg] = 1.0f / v;
    }

    #pragma unroll
    for (int n = 0; n < 4; ++n)
        #pragma unroll
        for (int reg = 0; reg < 16; ++reg)
            att_out[(size_t)(qrow + (reg & 3) + 8*(reg >> 2) + 4*h)*D_
                    + dz*128 + n*32 + col] = O[n][reg] * inv[reg];
}

// -------- K3: attn = E * (1/rowsum), elementwise, HBM-bound --------
__global__ __launch_bounds__(256) void norm_kernel(
    const unsigned short* __restrict__ Eb,
    const float* __restrict__ rowsum,
    float* __restrict__ attn_out)
{
    const int row = blockIdx.x;
    const int t   = threadIdx.x;
    const float inv = 1.0f / rowsum[row];
    const size_t base = (size_t)row * L_ + t*8;

    s8v e = *(const s8v*)(Eb + base);
    float4 o0, o1;
    o0.x = __builtin_bit_cast(float, ((unsigned)(unsigned short)e[0]) << 16) * inv;
    o0.y = __builtin_bit_cast(float, ((unsigned)(unsigned short)e[1]) << 16) * inv;
    o0.z = __builtin_bit_cast(float, ((unsigned)(unsigned short)e[2]) << 16) * inv;
    o0.w = __builtin_bit_cast(float, ((unsigned)(unsigned short)e[3]) << 16) * inv;
    o1.x = __builtin_bit_cast(float, ((unsigned)(unsigned short)e[4]) << 16) * inv;
    o1.y = __builtin_bit_cast(float, ((unsigned)(unsigned short)e[5]) << 16) * inv;
    o1.z = __builtin_bit_cast(float, ((unsigned)(unsigned short)e[6]) << 16) * inv;
    o1.w = __builtin_bit_cast(float, ((unsigned)(unsigned short)e[7]) << 16) * inv;
    *(float4*)(attn_out + base)     = o0;
    *(float4*)(attn_out + base + 4) = o1;
}

extern "C" void kernel_launch(void* const* d_in, const int* in_sizes, int n_in,
                              void* d_out, int out_size, void* d_ws, size_t ws_size,
                              hipStream_t stream) {
    (void)in_sizes; (void)n_in; (void)out_size; (void)ws_size;
    const float* x  = (const float*)d_in[0];
    const float* y  = (const float*)d_in[1];
    const unsigned char* mask = (const unsigned char*)d_in[2];
    const float* Wq = (const float*)d_in[3];
    const float* Wk = (const float*)d_in[4];
    const float* Wv = (const float*)d_in[5];

    // ws: Qb | Kf | Vf (bf16, 16.78 MB each) | qn | kn | rowsum | Eb (134 MB)
    char* ws = (char*)d_ws;
    unsigned short* Qb = (unsigned short*)ws;
    unsigned short* Kf = Qb + (size_t)NROW * D_;
    unsigned short* Vf = Kf + (size_t)NROW * D_;
    float* qn     = (float*)(ws + 3 * (size_t)NROW * D_ * 2);
    float* kn     = qn + NROW;
    float* rowsum = kn + NROW;
    unsigned short* Eb = (unsigned short*)(rowsum + NROW);

    float* att_out = (float*)d_out;                       // [B, LQ, D]
    float* attn    = att_out + (size_t)NROW * D_;         // [B, LQ, LK]

    qkv_kernel<<<dim3(512, 3), 256, 0, stream>>>(x, y, Wq, Wk, Wv,
                                                 Qb, Kf, Vf, qn, kn);
    attnpv_kernel<<<dim3(64, 16, 2), 64, 0, stream>>>(Qb, Kf, Vf, qn, kn, mask,
                                                      Eb, rowsum, att_out);
    norm_kernel<<<dim3(NROW), 256, 0, stream>>>(Eb, rowsum, attn);
}